// Round 2
// baseline (401.440 us; speedup 1.0000x reference)
//
#include <hip/hip_runtime.h>
#include <math.h>

#define TA 256
#define TB 320

// ---------------- Kernel A: conv1 + relu + pool, one thread per task ----------------
// task = (m, c, i, half): 7 pooled outputs. tasks per image = 6*14*2 = 168.
// No LDS, no syncs; x served by L1 (block working set ~8 KB); w1 preloaded to regs.
__global__ __launch_bounds__(TA, 5) void conv1_kernel(
    const float* __restrict__ x,
    const float* __restrict__ w1,
    float* __restrict__ p1g)     // [chunk][6][14][14]
{
    int gid = blockIdx.x * TA + threadIdx.x;
    int m = gid / 168;
    int r = gid - m * 168;
    int c = r % 6;
    int q = r / 6;            // 0..27
    int i = q >> 1;           // pooled row 0..13
    int half = q & 1;         // cols 7*half..7*half+6

    const float* xm = x + (size_t)m * 1024 + half * 14;

    float wreg[25];
    {
        const float* wc = w1 + c * 25;
        #pragma unroll
        for (int k = 0; k < 25; ++k) wreg[k] = wc[k];
    }

    float acc0[14], acc1[14];
    #pragma unroll
    for (int j = 0; j < 14; ++j) { acc0[j] = 0.f; acc1[j] = 0.f; }

    #pragma unroll
    for (int t = 0; t < 6; ++t) {
        float row[18];
        const float* rp = xm + (2 * i + t) * 32;
        #pragma unroll
        for (int qq = 0; qq < 9; ++qq) {
            float2 v = *(const float2*)(rp + 2 * qq);
            row[2 * qq] = v.x; row[2 * qq + 1] = v.y;
        }
        if (t < 5) {
            #pragma unroll
            for (int kx = 0; kx < 5; ++kx) {
                float w = wreg[t * 5 + kx];
                #pragma unroll
                for (int xx = 0; xx < 14; ++xx)
                    acc0[xx] = fmaf(row[xx + kx], w, acc0[xx]);
            }
        }
        if (t >= 1) {
            #pragma unroll
            for (int kx = 0; kx < 5; ++kx) {
                float w = wreg[(t - 1) * 5 + kx];
                #pragma unroll
                for (int xx = 0; xx < 14; ++xx)
                    acc1[xx] = fmaf(row[xx + kx], w, acc1[xx]);
            }
        }
    }

    float* dst = p1g + (size_t)m * 1176 + c * 196 + i * 14 + half * 7;
    #pragma unroll
    for (int j = 0; j < 7; ++j) {
        float v = fmaxf(fmaxf(acc0[2 * j], acc0[2 * j + 1]),
                        fmaxf(acc1[2 * j], acc1[2 * j + 1]));
        dst[j] = fmaxf(v, 0.f);
    }
}

// ---------------- Kernel B: conv2 + pool + fc1 + fc2 + fc3 + softmax ----------------
// 320 threads, 4 images per block. conv2: exactly 1 task per thread (320 = 4*16*5).
// LDS float offsets:
#define S_P1   0        // 4*1180 = 4720 (image stride 1180, channel stride 196)
#define S_W2   4720     // 2400
#define S_P2   7120     // 4*404 = 1616
#define LDSB   8736     // floats = 34,944 B -> 4 blocks/CU
// fc scratch aliases the P1 region after conv2 (p1 dead):
#define S_FC1P 0        // 960  ([m*120+n]*2 + h)
#define S_FC1  960      // 480  ([m*120+n])
#define S_FC2  1440     // 336  ([m*84+n])
#define S_LOG  1776     // 40

__global__ __launch_bounds__(TB, 5) void tail_kernel(
    const float* __restrict__ p1g,
    const float* __restrict__ w2,
    const float* __restrict__ fw1,
    const float* __restrict__ fw2,
    const float* __restrict__ fc3w,
    const float* __restrict__ fc3b,
    float* __restrict__ out,
    int img_off)
{
    __shared__ __align__(16) float lds[LDSB];
    const int tid = threadIdx.x;
    const int mb = blockIdx.x * 4;   // local image base within chunk

    // ---- stage p1 (4 images) + w2 into LDS ----
    {
        const float4* src = (const float4*)(p1g + (size_t)mb * 1176);
        for (int e = tid; e < 1176; e += TB) {         // 4*1176/4 = 1176 float4
            int m = e / 294;
            int k = e - m * 294;
            *(float4*)(lds + S_P1 + m * 1180 + k * 4) = src[e];
        }
        const float4* wsrc = (const float4*)w2;
        for (int e = tid; e < 600; e += TB)
            *(float4*)(lds + S_W2 + e * 4) = wsrc[e];
    }
    __syncthreads();

    // ---- conv2 (6->16, 5x5) + relu + pool. task = tid: (m, i, oc), oc innermost ----
    {
        int m = tid / 80;
        int r = tid - m * 80;
        int oc = r % 16;
        int i  = r / 16;              // pooled row 0..4
        const float* pim = lds + S_P1 + m * 1180;
        const float* wb  = lds + S_W2 + oc * 150;
        float acc0[10], acc1[10];
        #pragma unroll
        for (int j = 0; j < 10; ++j) { acc0[j] = 0.f; acc1[j] = 0.f; }
        for (int ic = 0; ic < 6; ++ic) {
            const float* pc = pim + ic * 196;
            const float* wc = wb + ic * 25;
            #pragma unroll
            for (int t = 0; t < 6; ++t) {
                float row[14];
                const float* rp = pc + (2 * i + t) * 14;
                #pragma unroll
                for (int qq = 0; qq < 7; ++qq) {
                    float2 v = *(const float2*)(rp + 2 * qq);
                    row[2 * qq] = v.x; row[2 * qq + 1] = v.y;
                }
                if (t < 5) {
                    #pragma unroll
                    for (int kx = 0; kx < 5; ++kx) {
                        float w = wc[t * 5 + kx];
                        #pragma unroll
                        for (int xx = 0; xx < 10; ++xx)
                            acc0[xx] = fmaf(row[xx + kx], w, acc0[xx]);
                    }
                }
                if (t >= 1) {
                    #pragma unroll
                    for (int kx = 0; kx < 5; ++kx) {
                        float w = wc[(t - 1) * 5 + kx];
                        #pragma unroll
                        for (int xx = 0; xx < 10; ++xx)
                            acc1[xx] = fmaf(row[xx + kx], w, acc1[xx]);
                    }
                }
            }
        }
        float* dst = lds + S_P2 + m * 404 + oc * 25 + i * 5;
        #pragma unroll
        for (int j = 0; j < 5; ++j) {
            float v = fmaxf(fmaxf(acc0[2 * j], acc0[2 * j + 1]),
                            fmaxf(acc1[2 * j], acc1[2 * j + 1]));
            dst[j] = fmaxf(v, 0.f);
        }
    }
    __syncthreads();

    // ---- fc1 partials: 960 tasks = 3 passes exact. task = (m, n, k-half) ----
    for (int t = tid; t < 960; t += TB) {
        int m = t & 3;
        int s = t >> 2;
        int n = s % 120;
        int h = s / 120;
        const float4* a = (const float4*)(lds + S_P2 + m * 404 + h * 200);
        const float4* w = (const float4*)(fw1 + n * 400 + h * 200);
        float acc = 0.f;
        #pragma unroll 5
        for (int k = 0; k < 50; ++k) {
            float4 av = a[k], wv = w[k];
            acc = fmaf(av.x, wv.x, acc);
            acc = fmaf(av.y, wv.y, acc);
            acc = fmaf(av.z, wv.z, acc);
            acc = fmaf(av.w, wv.w, acc);
        }
        lds[S_FC1P + (m * 120 + n) * 2 + h] = acc;
    }
    __syncthreads();

    // ---- fc1 reduce + relu: 480 elems ----
    for (int e = tid; e < 480; e += TB)
        lds[S_FC1 + e] = fmaxf(lds[S_FC1P + 2 * e] + lds[S_FC1P + 2 * e + 1], 0.f);
    __syncthreads();

    // ---- fc2: 336 tasks ----
    for (int t = tid; t < 336; t += TB) {
        int m = t & 3;
        int n = t >> 2;
        const float4* a = (const float4*)(lds + S_FC1 + m * 120);
        const float4* w = (const float4*)(fw2 + n * 120);
        float acc = 0.f;
        #pragma unroll
        for (int k = 0; k < 30; ++k) {
            float4 av = a[k], wv = w[k];
            acc = fmaf(av.x, wv.x, acc);
            acc = fmaf(av.y, wv.y, acc);
            acc = fmaf(av.z, wv.z, acc);
            acc = fmaf(av.w, wv.w, acc);
        }
        lds[S_FC2 + m * 84 + n] = fmaxf(acc, 0.f);
    }
    __syncthreads();

    // ---- fc3: 40 tasks ----
    if (tid < 40) {
        int m = tid & 3;
        int n = tid >> 2;
        const float4* a = (const float4*)(lds + S_FC2 + m * 84);
        const float4* w = (const float4*)(fc3w + n * 84);
        float acc = fc3b[n];
        #pragma unroll
        for (int k = 0; k < 21; ++k) {
            float4 av = a[k], wv = w[k];
            acc = fmaf(av.x, wv.x, acc);
            acc = fmaf(av.y, wv.y, acc);
            acc = fmaf(av.z, wv.z, acc);
            acc = fmaf(av.w, wv.w, acc);
        }
        lds[S_LOG + m * 10 + n] = acc;
    }
    __syncthreads();

    // ---- softmax, one thread per image ----
    if (tid < 4) {
        const float* lg = lds + S_LOG + tid * 10;
        float mx = lg[0];
        #pragma unroll
        for (int n = 1; n < 10; ++n) mx = fmaxf(mx, lg[n]);
        float e[10]; float sum = 0.f;
        #pragma unroll
        for (int n = 0; n < 10; ++n) { e[n] = expf(lg[n] - mx); sum += e[n]; }
        float inv = 1.f / sum;
        float* op = out + (size_t)(img_off + mb + tid) * 10;
        #pragma unroll
        for (int n = 0; n < 10; ++n) op[n] = e[n] * inv;
    }
}

extern "C" void kernel_launch(void* const* d_in, const int* in_sizes, int n_in,
                              void* d_out, int out_size, void* d_ws, size_t ws_size,
                              hipStream_t stream) {
    const float* x    = (const float*)d_in[0];
    const float* w1   = (const float*)d_in[1];
    const float* w2   = (const float*)d_in[2];
    const float* fw1  = (const float*)d_in[3];
    const float* fw2  = (const float*)d_in[4];
    const float* fc3w = (const float*)d_in[5];
    const float* fc3b = (const float*)d_in[6];
    float* outp = (float*)d_out;
    float* p1g  = (float*)d_ws;

    const int TOTAL = 16384;
    // largest power-of-two image chunk that fits ws (p1 = 1176 floats/img)
    size_t cap = ws_size / (1176 * sizeof(float));
    int chunk = TOTAL;
    while (chunk > 32 && (size_t)chunk > cap) chunk >>= 1;

    for (int off = 0; off < TOTAL; off += chunk) {
        dim3 gA(chunk * 168 / TA), bA(TA);
        hipLaunchKernelGGL(conv1_kernel, gA, bA, 0, stream,
                           x + (size_t)off * 1024, w1, p1g);
        dim3 gB(chunk / 4), bB(TB);
        hipLaunchKernelGGL(tail_kernel, gB, bB, 0, stream,
                           p1g, w2, fw1, fw2, fc3w, fc3b, outp, off);
    }
}

// Round 3
// 250.964 us; speedup vs baseline: 1.5996x; 1.5996x over previous
//
#include <hip/hip_runtime.h>
#include <math.h>

#define TH 320
#define IMG 4

// ---- LDS float offsets (8896 floats = 35.6 KB -> 4 blocks/CU) ----
#define S_P1   0        // 4*1180 (image stride 1180, channel stride 196)
#define S_W2   4720     // 2400
#define S_P2   7120     // 4*404 = 1616
#define S_W1   8736     // 150
#define LDS_TOT 8896
// fc scratch aliases P1 region after conv2 (p1 dead):
#define S_FC1P 0        // 960
#define S_FC1  960      // 480
#define S_FC2  1440     // 336
#define S_LOG  1776     // 40

__global__ __launch_bounds__(TH, 5) void lenet_kernel(
    const float* __restrict__ x,
    const float* __restrict__ w1,
    const float* __restrict__ w2,
    const float* __restrict__ fw1,
    const float* __restrict__ fw2,
    const float* __restrict__ fc3w,
    const float* __restrict__ fc3b,
    float* __restrict__ out)
{
    __shared__ __align__(16) float lds[LDS_TOT];
    const int tid = threadIdx.x;
    const int blk = blockIdx.x;

    // ---- stage conv weights into LDS (x stays in global, served by L1/L2) ----
    {
        const float4* wsrc = (const float4*)w2;
        for (int e = tid; e < 600; e += TH)
            *(float4*)(lds + S_W2 + e * 4) = wsrc[e];
        for (int e = tid; e < 150; e += TH) lds[S_W1 + e] = w1[e];
    }
    __syncthreads();

    // ---- conv1 (1->6, 5x5, 28x28) + relu + pool -> p1 in LDS ----
    // task = (m, c, i, half): 7 pooled outputs; 672 tasks (2.1 passes of 320)
    for (int task = tid; task < IMG * 168; task += TH) {
        int m = task / 168;
        int r = task - m * 168;
        int c = r % 6;           // c innermost: x addr independent of c -> L1 broadcast
        int q = r / 6;           // 0..27
        int i = q >> 1;          // pooled row 0..13
        int half = q & 1;        // cols 7*half..7*half+6

        const float* xm = x + ((size_t)(blk * IMG + m)) * 1024 + half * 14;
        const float* wc = lds + S_W1 + c * 25;

        float acc0[14], acc1[14];
        #pragma unroll
        for (int j = 0; j < 14; ++j) { acc0[j] = 0.f; acc1[j] = 0.f; }

        #pragma unroll
        for (int t = 0; t < 6; ++t) {
            float row[18];
            const float* rp = xm + (2 * i + t) * 32;
            #pragma unroll
            for (int qq = 0; qq < 9; ++qq) {
                float2 v = *(const float2*)(rp + 2 * qq);
                row[2 * qq] = v.x; row[2 * qq + 1] = v.y;
            }
            if (t < 5) {
                #pragma unroll
                for (int kx = 0; kx < 5; ++kx) {
                    float w = wc[t * 5 + kx];
                    #pragma unroll
                    for (int xx = 0; xx < 14; ++xx)
                        acc0[xx] = fmaf(row[xx + kx], w, acc0[xx]);
                }
            }
            if (t >= 1) {
                #pragma unroll
                for (int kx = 0; kx < 5; ++kx) {
                    float w = wc[(t - 1) * 5 + kx];
                    #pragma unroll
                    for (int xx = 0; xx < 14; ++xx)
                        acc1[xx] = fmaf(row[xx + kx], w, acc1[xx]);
                }
            }
        }
        float* dst = lds + S_P1 + m * 1180 + c * 196 + i * 14 + half * 7;
        #pragma unroll
        for (int j = 0; j < 7; ++j) {
            float v = fmaxf(fmaxf(acc0[2 * j], acc0[2 * j + 1]),
                            fmaxf(acc1[2 * j], acc1[2 * j + 1]));
            dst[j] = fmaxf(v, 0.f);
        }
    }
    __syncthreads();

    // ---- conv2 (6->16, 5x5) + relu + pool: exactly 1 task per thread ----
    {
        int m = tid / 80;
        int r = tid - m * 80;
        int oc = r % 16;          // oc innermost -> LDS input reads broadcast
        int i  = r / 16;          // pooled row 0..4
        const float* pim = lds + S_P1 + m * 1180;
        const float* wb  = lds + S_W2 + oc * 150;
        float acc0[10], acc1[10];
        #pragma unroll
        for (int j = 0; j < 10; ++j) { acc0[j] = 0.f; acc1[j] = 0.f; }
        for (int ic = 0; ic < 6; ++ic) {
            const float* pc = pim + ic * 196;
            const float* wc = wb + ic * 25;
            #pragma unroll
            for (int t = 0; t < 6; ++t) {
                float row[14];
                const float* rp = pc + (2 * i + t) * 14;
                #pragma unroll
                for (int qq = 0; qq < 7; ++qq) {
                    float2 v = *(const float2*)(rp + 2 * qq);
                    row[2 * qq] = v.x; row[2 * qq + 1] = v.y;
                }
                if (t < 5) {
                    #pragma unroll
                    for (int kx = 0; kx < 5; ++kx) {
                        float w = wc[t * 5 + kx];
                        #pragma unroll
                        for (int xx = 0; xx < 10; ++xx)
                            acc0[xx] = fmaf(row[xx + kx], w, acc0[xx]);
                    }
                }
                if (t >= 1) {
                    #pragma unroll
                    for (int kx = 0; kx < 5; ++kx) {
                        float w = wc[(t - 1) * 5 + kx];
                        #pragma unroll
                        for (int xx = 0; xx < 10; ++xx)
                            acc1[xx] = fmaf(row[xx + kx], w, acc1[xx]);
                    }
                }
            }
        }
        float* dst = lds + S_P2 + m * 404 + oc * 25 + i * 5;
        #pragma unroll
        for (int j = 0; j < 5; ++j) {
            float v = fmaxf(fmaxf(acc0[2 * j], acc0[2 * j + 1]),
                            fmaxf(acc1[2 * j], acc1[2 * j + 1]));
            dst[j] = fmaxf(v, 0.f);
        }
    }
    __syncthreads();

    // ---- fc1 partials: 960 tasks = 3 exact passes. task = (m, n, k-half) ----
    for (int t = tid; t < 960; t += TH) {
        int m = t & 3;
        int s = t >> 2;
        int n = s % 120;
        int h = s / 120;
        const float4* a = (const float4*)(lds + S_P2 + m * 404 + h * 200);
        const float4* w = (const float4*)(fw1 + n * 400 + h * 200);
        float acc = 0.f;
        #pragma unroll 5
        for (int k = 0; k < 50; ++k) {
            float4 av = a[k], wv = w[k];
            acc = fmaf(av.x, wv.x, acc);
            acc = fmaf(av.y, wv.y, acc);
            acc = fmaf(av.z, wv.z, acc);
            acc = fmaf(av.w, wv.w, acc);
        }
        lds[S_FC1P + (m * 120 + n) * 2 + h] = acc;
    }
    __syncthreads();

    // ---- fc1 reduce + relu ----
    for (int e = tid; e < 480; e += TH)
        lds[S_FC1 + e] = fmaxf(lds[S_FC1P + 2 * e] + lds[S_FC1P + 2 * e + 1], 0.f);
    __syncthreads();

    // ---- fc2: 336 tasks ----
    for (int t = tid; t < 336; t += TH) {
        int m = t & 3;
        int n = t >> 2;
        const float4* a = (const float4*)(lds + S_FC1 + m * 120);
        const float4* w = (const float4*)(fw2 + n * 120);
        float acc = 0.f;
        #pragma unroll
        for (int k = 0; k < 30; ++k) {
            float4 av = a[k], wv = w[k];
            acc = fmaf(av.x, wv.x, acc);
            acc = fmaf(av.y, wv.y, acc);
            acc = fmaf(av.z, wv.z, acc);
            acc = fmaf(av.w, wv.w, acc);
        }
        lds[S_FC2 + m * 84 + n] = fmaxf(acc, 0.f);
    }
    __syncthreads();

    // ---- fc3: 40 tasks ----
    if (tid < 40) {
        int m = tid & 3;
        int n = tid >> 2;
        const float4* a = (const float4*)(lds + S_FC2 + m * 84);
        const float4* w = (const float4*)(fc3w + n * 84);
        float acc = fc3b[n];
        #pragma unroll
        for (int k = 0; k < 21; ++k) {
            float4 av = a[k], wv = w[k];
            acc = fmaf(av.x, wv.x, acc);
            acc = fmaf(av.y, wv.y, acc);
            acc = fmaf(av.z, wv.z, acc);
            acc = fmaf(av.w, wv.w, acc);
        }
        lds[S_LOG + m * 10 + n] = acc;
    }
    __syncthreads();

    // ---- softmax, one thread per image ----
    if (tid < IMG) {
        const float* lg = lds + S_LOG + tid * 10;
        float mx = lg[0];
        #pragma unroll
        for (int n = 1; n < 10; ++n) mx = fmaxf(mx, lg[n]);
        float e[10]; float sum = 0.f;
        #pragma unroll
        for (int n = 0; n < 10; ++n) { e[n] = expf(lg[n] - mx); sum += e[n]; }
        float inv = 1.f / sum;
        float* op = out + ((size_t)blk * IMG + tid) * 10;
        #pragma unroll
        for (int n = 0; n < 10; ++n) op[n] = e[n] * inv;
    }
}

extern "C" void kernel_launch(void* const* d_in, const int* in_sizes, int n_in,
                              void* d_out, int out_size, void* d_ws, size_t ws_size,
                              hipStream_t stream) {
    const float* x    = (const float*)d_in[0];
    const float* w1   = (const float*)d_in[1];
    const float* w2   = (const float*)d_in[2];
    const float* fw1  = (const float*)d_in[3];
    const float* fw2  = (const float*)d_in[4];
    const float* fc3w = (const float*)d_in[5];
    const float* fc3b = (const float*)d_in[6];
    float* outp = (float*)d_out;

    dim3 grid(16384 / IMG), block(TH);
    hipLaunchKernelGGL(lenet_kernel, grid, block, 0, stream,
                       x, w1, w2, fw1, fw2, fc3w, fc3b, outp);
}